// Round 4
// baseline (384.927 us; speedup 1.0000x reference)
//
#include <hip/hip_runtime.h>
#include <cstddef>

#define BB   256   // batch
#define UU   8     // in_units
#define ISZ  1152  // in_size
#define JJ   10    // out_units
#define DD   16    // out_size
#define JD   (JJ*DD)        // 160
#define ICH  9              // i per s block
#define NCH  (ISZ/ICH)      // 128
#define ICA  4              // i per agreement block
#define NCA  (ISZ/ICA)      // 288
#define WROW (JJ*DD*UU)     // 1280 floats per i row of W

// ---------------- transpose: x[b,u,i] -> x2[i][b][u]; also init b_ij=1 ----------------
// grid (18 i-tiles, 8 b-tiles), block 256. LDS-tiled, conflict-free, coalesced both sides.
__global__ void transpose_x(const float* __restrict__ x, float* __restrict__ x2,
                            float* __restrict__ b_ij) {
    __shared__ float buf[32][8][65];   // [b_local][u][i_local(+pad)]
    int it = blockIdx.x;               // 18 tiles of 64 i
    int bt = blockIdx.y;               // 8 tiles of 32 b
    int i0 = it * 64, b0 = bt * 32;
    int t = threadIdx.x;
    int lane = t & 63, wv = t >> 6;

    int flat = blockIdx.y * 18 + blockIdx.x;
    if (flat < 45) b_ij[flat * 256 + t] = 1.0f;     // 45*256 = 11520

    // read: 256 rows (b_local,u) x 64 i, coalesced 256B per wave-row
    for (int rep = 0; rep < 64; ++rep) {
        int row = rep * 4 + wv;        // 0..255
        int bl = row >> 3, u = row & 7;
        buf[bl][u][lane] = x[(size_t)(b0 + bl) * (UU * ISZ) + (size_t)u * ISZ + i0 + lane];
    }
    __syncthreads();
    // write: per i_local, 256 contiguous floats (b_local,u), coalesced
    int bl = t >> 3, u = t & 7;
    for (int il = 0; il < 64; ++il) {
        x2[((size_t)(i0 + il) * BB + b0 + bl) * UU + u] = buf[bl][u][il];
    }
}

// ---------------- s step, register-blocked, fused softmax ----------------
// grid (NCH, 2 j-halves, 2 d-halves), block 256 = all b.
// Per block: 9 i x 5 j x 8 d. xv held in regs across the whole jj/dd nest.
__global__ __launch_bounds__(256, 2) void s_kernel(
        const float* __restrict__ x2, const float* __restrict__ W,
        const float* __restrict__ b_ij, float* __restrict__ s_part, int first) {
    int ic = blockIdx.x, jh = blockIdx.y, dh = blockIdx.z;
    int j0 = jh * 5, d0 = dh * 8, i0 = ic * ICH;
    int t = threadIdx.x;
    int lane = t & 63, wv = t >> 6;
    __shared__ float c_lds[5][ICH];
    __shared__ float minv[5][2];

    if (first) {
        if (t < 5 * ICH) c_lds[t / ICH][t % ICH] = 1.0f / 1152.0f;  // softmax(ones)
    } else {
        // one j per wave (wave 0 also does jj=4): full-i softmax, no cross-wave reduce
        for (int jj = wv; jj < 5; jj += 4) {
            const float* bp = b_ij + (size_t)(j0 + jj) * ISZ;
            float m = -1e30f;
            for (int k = lane; k < ISZ; k += 64) m = fmaxf(m, bp[k]);
#pragma unroll
            for (int off = 32; off; off >>= 1) m = fmaxf(m, __shfl_down(m, off, 64));
            m = __shfl(m, 0, 64);
            float s = 0.f;
            for (int k = lane; k < ISZ; k += 64) s += __expf(bp[k] - m);
#pragma unroll
            for (int off = 32; off; off >>= 1) s += __shfl_down(s, off, 64);
            if (lane == 0) { minv[jj][0] = m; minv[jj][1] = 1.f / s; }
        }
        __syncthreads();
        if (t < 5 * ICH) {
            int jj = t / ICH, ii = t % ICH;
            c_lds[jj][ii] = __expf(b_ij[(size_t)(j0 + jj) * ISZ + i0 + ii] - minv[jj][0]) * minv[jj][1];
        }
    }
    __syncthreads();

    int b = t;
    float4 xa[ICH], xb[ICH];
#pragma unroll
    for (int ii = 0; ii < ICH; ++ii) {
        const float4* p = (const float4*)(x2 + ((size_t)(i0 + ii) * BB + b) * UU);
        xa[ii] = p[0]; xb[ii] = p[1];
    }
    float acc[5][8];
#pragma unroll
    for (int jj = 0; jj < 5; ++jj)
#pragma unroll
        for (int dd = 0; dd < 8; ++dd) acc[jj][dd] = 0.f;

#pragma unroll
    for (int jj = 0; jj < 5; ++jj) {
#pragma unroll
        for (int ii = 0; ii < ICH; ++ii) {
            const float* Wp = W + (size_t)(i0 + ii) * WROW + (j0 + jj) * (DD * UU) + d0 * UU;
            float ci = c_lds[jj][ii];
#pragma unroll
            for (int dd = 0; dd < 8; ++dd) {
                float s = Wp[dd * 8 + 0] * xa[ii].x + Wp[dd * 8 + 1] * xa[ii].y
                        + Wp[dd * 8 + 2] * xa[ii].z + Wp[dd * 8 + 3] * xa[ii].w
                        + Wp[dd * 8 + 4] * xb[ii].x + Wp[dd * 8 + 5] * xb[ii].y
                        + Wp[dd * 8 + 6] * xb[ii].z + Wp[dd * 8 + 7] * xb[ii].w;
                acc[jj][dd] += ci * s;
            }
        }
    }
    // s_part[ic][b][jd]; 8 consecutive d -> two float4 stores per jj
#pragma unroll
    for (int jj = 0; jj < 5; ++jj) {
        float* sp = s_part + ((size_t)ic * BB + b) * JD + (j0 + jj) * DD + d0;
        ((float4*)sp)[0] = make_float4(acc[jj][0], acc[jj][1], acc[jj][2], acc[jj][3]);
        ((float4*)sp)[1] = make_float4(acc[jj][4], acc[jj][5], acc[jj][6], acc[jj][7]);
    }
}

// ---------------- reduce partials + squash; v[b][jd] and vT[jd][b] ----------------
__global__ void reduce_squash_kernel(const float* __restrict__ s_part,
                                     float* __restrict__ v, float* __restrict__ vT) {
    int b = blockIdx.x;
    int t = threadIdx.x;   // 192 threads, t<160 active
    __shared__ float sm[JD];
    float s = 0.f;
    if (t < JD) {
#pragma unroll 8
        for (int ic = 0; ic < NCH; ++ic) s += s_part[((size_t)ic * BB + b) * JD + t];
        sm[t] = s;
    }
    __syncthreads();
    if (t < JD) {
        int d = t & 15;
        float msq = 0.f;
#pragma unroll
        for (int j = 0; j < JJ; ++j) { float x = sm[j * DD + d]; msq += x * x; }
        float val = msq / (1.f + msq) * s * rsqrtf(msq);
        v[(size_t)b * JD + t] = val;
        vT[(size_t)t * BB + b] = val;
    }
}

// ---------------- agreement: b_ij[j][i] += (1/B) sum_{b,d} u_hat*v ----------------
// grid (NCA, 2 j-halves), block 256 = all b. Register-blocked 4 i x 5 j.
__global__ __launch_bounds__(256, 2) void agreement_kernel(
        const float* __restrict__ x2, const float* __restrict__ W,
        const float* __restrict__ vT, float* __restrict__ b_ij) {
    int ic = blockIdx.x, jh = blockIdx.y;
    int j0 = jh * 5, i0 = ic * ICA;
    int b = threadIdx.x;
    int lane = b & 63, wv = b >> 6;

    float vv[5][16];
#pragma unroll
    for (int jj = 0; jj < 5; ++jj)
#pragma unroll
        for (int dd = 0; dd < 16; ++dd)
            vv[jj][dd] = vT[(size_t)((j0 + jj) * DD + dd) * BB + b];   // coalesced

    float4 xa[ICA], xb[ICA];
#pragma unroll
    for (int ii = 0; ii < ICA; ++ii) {
        const float4* p = (const float4*)(x2 + ((size_t)(i0 + ii) * BB + b) * UU);
        xa[ii] = p[0]; xb[ii] = p[1];
    }

    float acc[5][ICA];
#pragma unroll
    for (int jj = 0; jj < 5; ++jj) {
#pragma unroll
        for (int ii = 0; ii < ICA; ++ii) {
            const float* Wp = W + (size_t)(i0 + ii) * WROW + (j0 + jj) * (DD * UU);
            float sum = 0.f;
#pragma unroll
            for (int dd = 0; dd < 16; ++dd) {
                float s = Wp[dd * 8 + 0] * xa[ii].x + Wp[dd * 8 + 1] * xa[ii].y
                        + Wp[dd * 8 + 2] * xa[ii].z + Wp[dd * 8 + 3] * xa[ii].w
                        + Wp[dd * 8 + 4] * xb[ii].x + Wp[dd * 8 + 5] * xb[ii].y
                        + Wp[dd * 8 + 6] * xb[ii].z + Wp[dd * 8 + 7] * xb[ii].w;
                sum += s * vv[jj][dd];
            }
            acc[jj][ii] = sum;
        }
    }

    __shared__ float red[4][5][ICA];
#pragma unroll
    for (int jj = 0; jj < 5; ++jj)
#pragma unroll
        for (int ii = 0; ii < ICA; ++ii) {
            float a = acc[jj][ii];
#pragma unroll
            for (int off = 32; off; off >>= 1) a += __shfl_down(a, off, 64);
            if (lane == 0) red[wv][jj][ii] = a;
        }
    __syncthreads();
    if (b < 5 * ICA) {
        int jj = b / ICA, ii = b % ICA;
        float r = red[0][jj][ii] + red[1][jj][ii] + red[2][jj][ii] + red[3][jj][ii];
        b_ij[(size_t)(j0 + jj) * ISZ + i0 + ii] += r * (1.0f / (float)BB);
    }
}

extern "C" void kernel_launch(void* const* d_in, const int* in_sizes, int n_in,
                              void* d_out, int out_size, void* d_ws, size_t ws_size,
                              hipStream_t stream) {
    const float* x = (const float*)d_in[0];   // (256, 8, 1152)
    const float* W = (const float*)d_in[1];   // (1, 1152, 10, 16, 8)
    float* out = (float*)d_out;               // (256, 10, 16, 1) -> v

    float* x2     = (float*)d_ws;                   // 1152*256*8 = 2,359,296 floats
    float* b_ij   = x2 + (size_t)ISZ * BB * UU;     // 11,520
    float* vT     = b_ij + ISZ * JJ;                // 160*256 = 40,960
    float* s_part = vT + JD * BB;                   // 128*256*160 = 5,242,880 floats
    float* v      = out;

    hipLaunchKernelGGL(transpose_x, dim3(18, 8), dim3(256), 0, stream, x, x2, b_ij);

    for (int it = 0; it < 3; ++it) {
        hipLaunchKernelGGL(s_kernel, dim3(NCH, 2, 2), dim3(256), 0, stream,
                           x2, W, b_ij, s_part, it == 0 ? 1 : 0);
        hipLaunchKernelGGL(reduce_squash_kernel, dim3(BB), dim3(192), 0, stream,
                           s_part, v, vT);
        if (it < 2) {
            hipLaunchKernelGGL(agreement_kernel, dim3(NCA, 2), dim3(256), 0, stream,
                               x2, W, vT, b_ij);
        }
    }
}